// Round 1
// baseline (13176.845 us; speedup 1.0000x reference)
//
#include <hip/hip_runtime.h>
#include <math.h>

#define BB 64
#define TT 32
#define II 512
#define HH 1024
#define OO 512
#define RR 1
#define NN 1024
#define MM 64
#define SS 3
#define EPSF 1e-8f

struct P {
  const float *Wk_r,*bk_r,*Wb_r,*bb_r,*Wg_r,*bg_r,*Ws_r,*bs_r,*Wga_r,*bga_r;
  const float *Wk_w,*bk_w,*Wb_w,*bb_w,*Wg_w,*bg_w,*Ws_w,*bs_w,*Wga_w,*bga_w;
  const float *We,*be,*Wa,*ba,*W_r2i,*b_r2i,*Wih,*bih,*Whh,*bhh,*Who,*bho;
  const float *x;
  float *outs, *wr, *ww, *mem;
  float *kv, *beta, *g, *gamma, *s, *knorm, *e, *a, *r, *xi;
  float *gi_part, *gh_part, *out_part;
};

__device__ __forceinline__ float sigmf(float x){ return 1.f/(1.f+expf(-x)); }
__device__ __forceinline__ float splusf(float x){ return fmaxf(x,0.f) + log1pf(expf(-fabsf(x))); }

// ---------------- gates: all projections of h ----------------
// 268 outputs per b: [k_r(64), beta_r, g_r, s_r(3), gamma_r] , same for write head,
// e(64), a(64). Wave-per-output dot over H=1024 from LDS-cached h row.
__global__ __launch_bounds__(256) void gates_kernel(P p, const float* __restrict__ h) {
  __shared__ float h_s[HH];
  __shared__ float kv_s[2][MM];
  __shared__ float sv_s[2][SS];
  int b = blockIdx.x;
  int t = threadIdx.x;
  // load h row (coalesced float4)
  ((float4*)h_s)[t] = ((const float4*)(h + (size_t)b*HH))[t];   // 256 * 4 = 1024
  __syncthreads();
  int wv = t >> 6, lane = t & 63;
  for (int j = wv; j < 268; j += 4) {
    const float* Wrow = nullptr; float bias = 0.f; int act = 0;
    float* gdst = nullptr; int kvh = -1, kvm = 0, shh = -1, ssi = 0;
    if (j < 140) {
      int head = (j < 70) ? 0 : 1;
      int q = j - head*70;
      if (q < 64) {
        Wrow = (head ? p.Wk_w : p.Wk_r) + q*HH;
        bias = (head ? p.bk_w : p.bk_r)[q];
        act = 0; gdst = p.kv + (head*BB + b)*MM + q; kvh = head; kvm = q;
      } else if (q == 64) {
        Wrow = head ? p.Wb_w : p.Wb_r; bias = (head ? p.bb_w : p.bb_r)[0];
        act = 1; gdst = p.beta + head*BB + b;
      } else if (q == 65) {
        Wrow = head ? p.Wg_w : p.Wg_r; bias = (head ? p.bg_w : p.bg_r)[0];
        act = 2; gdst = p.g + head*BB + b;
      } else if (q < 69) {
        int i2 = q - 66;
        Wrow = (head ? p.Ws_w : p.Ws_r) + i2*HH; bias = (head ? p.bs_w : p.bs_r)[i2];
        act = 3; shh = head; ssi = i2;
      } else {
        Wrow = head ? p.Wga_w : p.Wga_r; bias = (head ? p.bga_w : p.bga_r)[0];
        act = 4; gdst = p.gamma + head*BB + b;
      }
    } else if (j < 204) {
      int m = j - 140; Wrow = p.We + m*HH; bias = p.be[m]; act = 2; gdst = p.e + b*MM + m;
    } else {
      int m = j - 204; Wrow = p.Wa + m*HH; bias = p.ba[m]; act = 0; gdst = p.a + b*MM + m;
    }
    float acc = 0.f;
    #pragma unroll
    for (int i = 0; i < 16; ++i) acc += Wrow[lane + 64*i] * h_s[lane + 64*i];
    #pragma unroll
    for (int off = 32; off; off >>= 1) acc += __shfl_down(acc, off);
    if (lane == 0) {
      float v = acc + bias;
      if (act == 0) v = tanhf(v);
      else if (act == 1) v = splusf(v);
      else if (act == 2) v = sigmf(v);
      else if (act == 4) v = 1.f + splusf(v);
      if (gdst) *gdst = v;
      if (kvh >= 0) kv_s[kvh][kvm] = v;
      if (shh >= 0) sv_s[shh][ssi] = v;
    }
  }
  __syncthreads();
  if (wv < 2) {   // k-norm per head
    float v = kv_s[wv][lane];
    float q = v * v;
    #pragma unroll
    for (int off = 32; off; off >>= 1) q += __shfl_down(q, off);
    if (lane == 0) p.knorm[wv*BB + b] = sqrtf(q);
  }
  if (t < 2) {    // shift softmax (3 values) per head
    int head = t;
    float a0 = sv_s[head][0], a1 = sv_s[head][1], a2 = sv_s[head][2];
    float mx = fmaxf(a0, fmaxf(a1, a2));
    float e0 = expf(a0-mx), e1 = expf(a1-mx), e2 = expf(a2-mx);
    float inv = 1.f/(e0+e1+e2);
    p.s[(head*BB + b)*SS + 0] = e0*inv;
    p.s[(head*BB + b)*SS + 1] = e1*inv;
    p.s[(head*BB + b)*SS + 2] = e2*inv;
  }
}

// ---------------- address: full NTM addressing per (head, b) ----------------
__global__ __launch_bounds__(256) void address_kernel(P p) {
  int b = blockIdx.x >> 1, head = blockIdx.x & 1;
  float* wbuf = head ? p.ww : p.wr;   // (B,N), updated in place
  __shared__ float k_s[MM];
  __shared__ float wprev_s[NN];
  __shared__ float pp[NN];
  __shared__ float wg_s[NN];
  __shared__ float red[256];
  int t = threadIdx.x, wv = t >> 6, lane = t & 63;
  if (t < MM) k_s[t] = p.kv[(head*BB + b)*MM + t];
  for (int i = t; i < NN; i += 256) wprev_s[i] = wbuf[(size_t)b*NN + i];
  float beta = p.beta[head*BB + b];
  float g    = p.g[head*BB + b];
  float gam  = p.gamma[head*BB + b];
  float kn   = p.knorm[head*BB + b];
  float s0 = p.s[(head*BB + b)*SS + 0];
  float s1 = p.s[(head*BB + b)*SS + 1];
  float s2 = p.s[(head*BB + b)*SS + 2];
  __syncthreads();
  const float* memb = p.mem + (size_t)b*NN*MM;
  for (int n = wv; n < NN; n += 4) {
    float v = memb[(size_t)n*MM + lane];
    float d = k_s[lane]*v, q = v*v;
    #pragma unroll
    for (int off = 32; off; off >>= 1) { d += __shfl_down(d, off); q += __shfl_down(q, off); }
    if (lane == 0) pp[n] = beta * (d / (kn * sqrtf(q) + EPSF));
  }
  __syncthreads();
  // softmax over N
  float m = -1e30f;
  for (int i = t; i < NN; i += 256) m = fmaxf(m, pp[i]);
  red[t] = m; __syncthreads();
  for (int off = 128; off; off >>= 1) { if (t < off) red[t] = fmaxf(red[t], red[t+off]); __syncthreads(); }
  m = red[0]; __syncthreads();
  float sm = 0.f;
  for (int i = t; i < NN; i += 256) { float e = expf(pp[i]-m); pp[i] = e; sm += e; }
  red[t] = sm; __syncthreads();
  for (int off = 128; off; off >>= 1) { if (t < off) red[t] += red[t+off]; __syncthreads(); }
  float invs = 1.f/red[0]; __syncthreads();
  // interpolate
  for (int i = t; i < NN; i += 256) wg_s[i] = g*(pp[i]*invs) + (1.f-g)*wprev_s[i];
  __syncthreads();
  // shift + sharpen
  float psum = 0.f;
  for (int i = t; i < NN; i += 256) {
    int im = (i == 0) ? NN-1 : i-1;
    int ip = (i == NN-1) ? 0 : i+1;
    float wt = s0*wg_s[im] + s1*wg_s[i] + s2*wg_s[ip];
    float w = powf(wt + 1e-12f, gam);
    pp[i] = w; psum += w;
  }
  red[t] = psum; __syncthreads();
  for (int off = 128; off; off >>= 1) { if (t < off) red[t] += red[t+off]; __syncthreads(); }
  float inv = 1.f/(red[0] + EPSF);
  for (int i = t; i < NN; i += 256) wbuf[(size_t)b*NN + i] = pp[i]*inv;
}

// ---------------- read vector + in-place memory erase/add ----------------
__global__ __launch_bounds__(256) void readmem_kernel(P p) {
  int b = blockIdx.x, t = threadIdx.x, wv = t >> 6, lane = t & 63;
  __shared__ float e_s[MM], a_s[MM], rp[4][MM];
  if (t < MM) { e_s[t] = p.e[b*MM + t]; a_s[t] = p.a[b*MM + t]; }
  __syncthreads();
  float racc = 0.f;
  float* memb = p.mem + (size_t)b*NN*MM;
  const float* wrb = p.wr + (size_t)b*NN;
  const float* wwb = p.ww + (size_t)b*NN;
  for (int n = wv; n < NN; n += 4) {
    float wrv = wrb[n], wwv = wwb[n];
    float v = memb[(size_t)n*MM + lane];
    racc += wrv * v;
    memb[(size_t)n*MM + lane] = v*(1.f - wwv*e_s[lane]) + wwv*a_s[lane];
  }
  rp[wv][lane] = racc;
  __syncthreads();
  if (wv == 0) p.r[b*MM + lane] = rp[0][lane]+rp[1][lane]+rp[2][lane]+rp[3][lane];
}

// ---------------- rin + xi ----------------
__global__ __launch_bounds__(256) void rinxi_kernel(P p, int tstep) {
  int b = blockIdx.x, t = threadIdx.x, wv = t >> 6, lane = t & 63;
  __shared__ float r_s[MM];
  if (t < MM) r_s[t] = p.r[b*MM + t];
  __syncthreads();
  for (int i = wv; i < II; i += 4) {
    float acc = r_s[lane] * p.W_r2i[(size_t)i*MM + lane];
    #pragma unroll
    for (int off = 32; off; off >>= 1) acc += __shfl_down(acc, off);
    if (lane == 0) {
      float rin = fmaxf(acc + p.b_r2i[i], 0.f);
      float xv = p.x[((size_t)b*TT + tstep)*II + i];
      p.xi[(size_t)b*II + i] = fmaxf(xv + rin, 0.f);
    }
  }
}

// ---------------- tiled split-K matmul: part[c][b][j] = sum_{k in chunk c} in[b,k]*W[j,k] ----------------
__global__ __launch_bounds__(256) void matmul_part_kernel(
    const float* __restrict__ in, const float* __restrict__ W,
    float* __restrict__ part, int K, int Jtot) {
  __shared__ float As[16][68];
  __shared__ float Ws[16][68];
  int t = threadIdx.x;
  int jt = blockIdx.x * 64;
  int k0base = blockIdx.y * 256;
  int tb = (t & 15) * 4;
  int tj = (t >> 4) * 4;
  int lb = t >> 2;
  int lk = (t & 3) * 4;
  float a00=0,a01=0,a02=0,a03=0, a10=0,a11=0,a12=0,a13=0;
  float a20=0,a21=0,a22=0,a23=0, a30=0,a31=0,a32=0,a33=0;
  const float* inp = in + (size_t)lb*K + k0base + lk;
  const float* wp  = W  + (size_t)(jt + lb)*K + k0base + lk;
  for (int kc = 0; kc < 256; kc += 16) {
    float4 av = *(const float4*)(inp + kc);
    float4 wv = *(const float4*)(wp + kc);
    __syncthreads();
    As[lk+0][lb]=av.x; As[lk+1][lb]=av.y; As[lk+2][lb]=av.z; As[lk+3][lb]=av.w;
    Ws[lk+0][lb]=wv.x; Ws[lk+1][lb]=wv.y; Ws[lk+2][lb]=wv.z; Ws[lk+3][lb]=wv.w;
    __syncthreads();
    #pragma unroll
    for (int kk = 0; kk < 16; ++kk) {
      float4 a4 = *(const float4*)&As[kk][tb];
      float4 w4 = *(const float4*)&Ws[kk][tj];
      a00 += a4.x*w4.x; a01 += a4.x*w4.y; a02 += a4.x*w4.z; a03 += a4.x*w4.w;
      a10 += a4.y*w4.x; a11 += a4.y*w4.y; a12 += a4.y*w4.z; a13 += a4.y*w4.w;
      a20 += a4.z*w4.x; a21 += a4.z*w4.y; a22 += a4.z*w4.z; a23 += a4.z*w4.w;
      a30 += a4.w*w4.x; a31 += a4.w*w4.y; a32 += a4.w*w4.z; a33 += a4.w*w4.w;
    }
  }
  size_t base = ((size_t)blockIdx.y*BB + tb)*Jtot + jt + tj;
  float* d0 = part + base;
  d0[0]=a00; d0[1]=a01; d0[2]=a02; d0[3]=a03; d0 += Jtot;
  d0[0]=a10; d0[1]=a11; d0[2]=a12; d0[3]=a13; d0 += Jtot;
  d0[0]=a20; d0[1]=a21; d0[2]=a22; d0[3]=a23; d0 += Jtot;
  d0[0]=a30; d0[1]=a31; d0[2]=a32; d0[3]=a33;
}

// ---------------- GRU combine ----------------
__global__ __launch_bounds__(256) void gru_combine_kernel(P p, const float* __restrict__ hold,
                                                          float* __restrict__ hnew) {
  int idx = blockIdx.x*256 + threadIdx.x;      // < B*H
  int b = idx >> 10, j = idx & (HH-1);
  const size_t row = (size_t)b*3*HH;
  const float* gi = p.gi_part;
  const float* gh = p.gh_part;
  const size_t stride = (size_t)BB*3*HH;
  float ir = gi[row + j]        + gi[stride + row + j]        + p.bih[j];
  float iz = gi[row + j + HH]   + gi[stride + row + j + HH]   + p.bih[j + HH];
  float in_= gi[row + j + 2*HH] + gi[stride + row + j + 2*HH] + p.bih[j + 2*HH];
  float hr = gh[row + j]        + gh[stride + row + j]
           + gh[2*stride + row + j]        + gh[3*stride + row + j]        + p.bhh[j];
  float hz = gh[row + j + HH]   + gh[stride + row + j + HH]
           + gh[2*stride + row + j + HH]   + gh[3*stride + row + j + HH]   + p.bhh[j + HH];
  float hn = gh[row + j + 2*HH] + gh[stride + row + j + 2*HH]
           + gh[2*stride + row + j + 2*HH] + gh[3*stride + row + j + 2*HH] + p.bhh[j + 2*HH];
  float rr = sigmf(ir + hr);
  float zz = sigmf(iz + hz);
  float nn = tanhf(in_ + rr*hn);
  hnew[idx] = (1.f - zz)*nn + zz*hold[idx];
}

// ---------------- output head finalize ----------------
__global__ __launch_bounds__(256) void out_final_kernel(P p, int tstep) {
  int idx = blockIdx.x*256 + threadIdx.x;      // < B*O
  int b = idx >> 9, o = idx & (OO-1);
  float acc = p.bho[o];
  #pragma unroll
  for (int c = 0; c < 4; ++c) acc += p.out_part[((size_t)c*BB + b)*OO + o];
  p.outs[((size_t)b*TT + tstep)*OO + o] = sigmf(acc);
}

extern "C" void kernel_launch(void* const* d_in, const int* in_sizes, int n_in,
                              void* d_out, int out_size, void* d_ws, size_t ws_size,
                              hipStream_t stream) {
  const float* x    = (const float*)d_in[0];
  const float* h0   = (const float*)d_in[1];
  const float* wr0  = (const float*)d_in[2];
  const float* ww0  = (const float*)d_in[3];
  const float* mem0 = (const float*)d_in[4];
  P p;
  int i = 5;
  p.Wk_r  = (const float*)d_in[i++]; p.bk_r  = (const float*)d_in[i++];
  p.Wb_r  = (const float*)d_in[i++]; p.bb_r  = (const float*)d_in[i++];
  p.Wg_r  = (const float*)d_in[i++]; p.bg_r  = (const float*)d_in[i++];
  p.Ws_r  = (const float*)d_in[i++]; p.bs_r  = (const float*)d_in[i++];
  p.Wga_r = (const float*)d_in[i++]; p.bga_r = (const float*)d_in[i++];
  p.Wk_w  = (const float*)d_in[i++]; p.bk_w  = (const float*)d_in[i++];
  p.Wb_w  = (const float*)d_in[i++]; p.bb_w  = (const float*)d_in[i++];
  p.Wg_w  = (const float*)d_in[i++]; p.bg_w  = (const float*)d_in[i++];
  p.Ws_w  = (const float*)d_in[i++]; p.bs_w  = (const float*)d_in[i++];
  p.Wga_w = (const float*)d_in[i++]; p.bga_w = (const float*)d_in[i++];
  p.We    = (const float*)d_in[i++]; p.be    = (const float*)d_in[i++];
  p.Wa    = (const float*)d_in[i++]; p.ba    = (const float*)d_in[i++];
  p.W_r2i = (const float*)d_in[i++]; p.b_r2i = (const float*)d_in[i++];
  p.Wih   = (const float*)d_in[i++]; p.bih   = (const float*)d_in[i++];
  p.Whh   = (const float*)d_in[i++]; p.bhh   = (const float*)d_in[i++];
  p.Who   = (const float*)d_in[i++]; p.bho   = (const float*)d_in[i++];
  p.x = x;

  float* out = (float*)d_out;
  p.outs = out;                                  // (B,T,O)
  float* hOut = out + (size_t)BB*TT*OO;          // (B,H) final h
  p.wr  = hOut + (size_t)BB*HH;                  // (B,N) (R=1)
  p.ww  = p.wr + (size_t)BB*NN;                  // (B,N)
  p.mem = p.ww + (size_t)BB*NN;                  // (B,N,M)

  float* ws = (float*)d_ws;
  float* hAlt = ws;          ws += (size_t)BB*HH;
  p.kv       = ws;           ws += 2*BB*MM;
  p.beta     = ws;           ws += 2*BB;
  p.g        = ws;           ws += 2*BB;
  p.gamma    = ws;           ws += 2*BB;
  p.s        = ws;           ws += 2*BB*SS;
  p.knorm    = ws;           ws += 2*BB;
  p.e        = ws;           ws += BB*MM;
  p.a        = ws;           ws += BB*MM;
  p.r        = ws;           ws += BB*MM;
  p.xi       = ws;           ws += (size_t)BB*II;
  p.gi_part  = ws;           ws += (size_t)2*BB*3*HH;
  p.gh_part  = ws;           ws += (size_t)4*BB*3*HH;
  p.out_part = ws;           ws += (size_t)4*BB*OO;

  // initialize state in d_out
  hipMemcpyAsync(hOut,  h0,   (size_t)BB*HH*sizeof(float),    hipMemcpyDeviceToDevice, stream);
  hipMemcpyAsync(p.wr,  wr0,  (size_t)BB*NN*sizeof(float),    hipMemcpyDeviceToDevice, stream);
  hipMemcpyAsync(p.ww,  ww0,  (size_t)BB*NN*sizeof(float),    hipMemcpyDeviceToDevice, stream);
  hipMemcpyAsync(p.mem, mem0, (size_t)BB*NN*MM*sizeof(float), hipMemcpyDeviceToDevice, stream);

  float* hbuf[2] = { hOut, hAlt };   // t even reads hbuf[0]; 32 steps end back in hbuf[0] = d_out
  for (int t = 0; t < TT; ++t) {
    const float* hc = hbuf[t & 1];
    float* hn = hbuf[(t + 1) & 1];
    gates_kernel<<<BB, 256, 0, stream>>>(p, hc);
    address_kernel<<<2*BB, 256, 0, stream>>>(p);
    readmem_kernel<<<BB, 256, 0, stream>>>(p);
    rinxi_kernel<<<BB, 256, 0, stream>>>(p, t);
    matmul_part_kernel<<<dim3(3*HH/64, II/256), 256, 0, stream>>>(p.xi, p.Wih, p.gi_part, II, 3*HH);
    matmul_part_kernel<<<dim3(3*HH/64, HH/256), 256, 0, stream>>>(hc,  p.Whh, p.gh_part, HH, 3*HH);
    gru_combine_kernel<<<BB*HH/256, 256, 0, stream>>>(p, hc, hn);
    matmul_part_kernel<<<dim3(OO/64, HH/256), 256, 0, stream>>>(hn, p.Who, p.out_part, HH, OO);
    out_final_kernel<<<BB*OO/256, 256, 0, stream>>>(p, t);
  }
}